// Round 2
// baseline (423.544 us; speedup 1.0000x reference)
//
#include <hip/hip_runtime.h>

#define TT 16384
#define CC 4096
#define NE 64
#define TOPK 2
#define ALPHA 0.01f
#define CSPLIT 4
#define KRANGE (CC / CSPLIT)   // 1024
#define BK 32
#define BT 128
#define NCHUNK (KRANGE / BK)   // 32

// ---------------- GEMM: partial logits = x[t0:t0+128, k0:k0+1024] @ w^T ----------------
__global__ __launch_bounds__(256, 2) void gate_gemm(const float* __restrict__ x,
                                                    const float* __restrict__ w,
                                                    float* __restrict__ part) {
    __shared__ float xs[BK][BT + 4];   // [kk][t], pad 132 floats: conflict-free b128 reads
    __shared__ float wsh[BK][NE + 4];  // [kk][e], pad 68 floats: 2-way (free) b128 reads

    const int tile = blockIdx.x;
    const int cs   = blockIdx.y;
    const int t0   = tile * BT;
    const int k0   = cs * KRANGE;
    const int tid  = threadIdx.x;
    const int tg   = tid >> 3;   // 0..31
    const int eg   = tid & 7;    // 0..7
    const int tloc = tg << 2;    // 0..124 (4 tokens per thread)
    const int e0   = eg << 3;    // 0..56  (8 experts per thread)

    float acc[4][8];
#pragma unroll
    for (int i = 0; i < 4; ++i)
#pragma unroll
        for (int j = 0; j < 8; ++j) acc[i][j] = 0.f;

    const float* xb = x + (size_t)t0 * CC + k0;
    const float* wb = w + k0;

    float4 xr[4], wr[2];
    // prefetch chunk 0 into registers (coalesced: 8 lanes cover 128B rows)
#pragma unroll
    for (int it = 0; it < 4; ++it)
        xr[it] = *(const float4*)(xb + (size_t)(tg + 32 * it) * CC + (eg << 2));
#pragma unroll
    for (int it = 0; it < 2; ++it)
        wr[it] = *(const float4*)(wb + (size_t)(tg + 32 * it) * CC + (eg << 2));

    for (int kc = 0; kc < NCHUNK; ++kc) {
        __syncthreads();
        // regs -> LDS (transposed store)
#pragma unroll
        for (int it = 0; it < 4; ++it) {
            const int r = tg + 32 * it;
            const int c = eg << 2;
            xs[c + 0][r] = xr[it].x;
            xs[c + 1][r] = xr[it].y;
            xs[c + 2][r] = xr[it].z;
            xs[c + 3][r] = xr[it].w;
        }
#pragma unroll
        for (int it = 0; it < 2; ++it) {
            const int e = tg + 32 * it;
            const int c = eg << 2;
            wsh[c + 0][e] = wr[it].x;
            wsh[c + 1][e] = wr[it].y;
            wsh[c + 2][e] = wr[it].z;
            wsh[c + 3][e] = wr[it].w;
        }
        __syncthreads();
        // prefetch next chunk (overlaps with compute below)
        if (kc + 1 < NCHUNK) {
            const int ko = (kc + 1) * BK;
#pragma unroll
            for (int it = 0; it < 4; ++it)
                xr[it] = *(const float4*)(xb + (size_t)(tg + 32 * it) * CC + ko + (eg << 2));
#pragma unroll
            for (int it = 0; it < 2; ++it)
                wr[it] = *(const float4*)(wb + (size_t)(tg + 32 * it) * CC + ko + (eg << 2));
        }
        // inner loop: per k, 3x ds_read_b128 + 32 FMA
#pragma unroll
        for (int kk = 0; kk < BK; ++kk) {
            const float4 xa  = *(const float4*)&xs[kk][tloc];
            const float4 wa  = *(const float4*)&wsh[kk][e0];
            const float4 wbv = *(const float4*)&wsh[kk][e0 + 4];
            const float xv[4] = {xa.x, xa.y, xa.z, xa.w};
            const float wv[8] = {wa.x, wa.y, wa.z, wa.w, wbv.x, wbv.y, wbv.z, wbv.w};
#pragma unroll
            for (int i = 0; i < 4; ++i)
#pragma unroll
                for (int j = 0; j < 8; ++j) acc[i][j] = fmaf(xv[i], wv[j], acc[i][j]);
        }
    }

    // epilogue: write partial logits [cs][t][e]
    float* pb = part + (size_t)cs * TT * NE + (size_t)(t0 + tloc) * NE + e0;
#pragma unroll
    for (int i = 0; i < 4; ++i) {
        *(float4*)(pb + (size_t)i * NE)     = make_float4(acc[i][0], acc[i][1], acc[i][2], acc[i][3]);
        *(float4*)(pb + (size_t)i * NE + 4) = make_float4(acc[i][4], acc[i][5], acc[i][6], acc[i][7]);
    }
}

// ---------------- finalize: reduce partials, softmax, top-2, Pi/count accumulation ----------------
__global__ __launch_bounds__(256) void finalize(const float* __restrict__ part,
                                                float* __restrict__ out,
                                                float* __restrict__ Pacc,
                                                float* __restrict__ Cacc) {
    __shared__ float Ps[NE];
    __shared__ float Csh[NE];
    const int tid = threadIdx.x;
    const int t   = blockIdx.x * 256 + tid;
    if (tid < NE) {
        Ps[tid]  = 0.f;
        Csh[tid] = 0.f;
    }
    __syncthreads();

    float l[NE];
#pragma unroll
    for (int e4 = 0; e4 < 16; ++e4) {
        const float4 v = *(const float4*)(part + (size_t)t * NE + e4 * 4);
        l[e4 * 4 + 0] = v.x;
        l[e4 * 4 + 1] = v.y;
        l[e4 * 4 + 2] = v.z;
        l[e4 * 4 + 3] = v.w;
    }
#pragma unroll
    for (int cs = 1; cs < CSPLIT; ++cs) {
#pragma unroll
        for (int e4 = 0; e4 < 16; ++e4) {
            const float4 v = *(const float4*)(part + (size_t)cs * TT * NE + (size_t)t * NE + e4 * 4);
            l[e4 * 4 + 0] += v.x;
            l[e4 * 4 + 1] += v.y;
            l[e4 * 4 + 2] += v.z;
            l[e4 * 4 + 3] += v.w;
        }
    }

    // top-2 scan (strict > keeps lowest index on ties, like lax.top_k)
    float m1 = -3.402823466e+38f, m2 = -3.402823466e+38f;
    int   i1 = 0, i2 = 0;
#pragma unroll
    for (int e = 0; e < NE; ++e) {
        const float v = l[e];
        if (v > m1) {
            m2 = m1; i2 = i1;
            m1 = v;  i1 = e;
        } else if (v > m2) {
            m2 = v; i2 = e;
        }
    }

    // softmax (max = m1)
    float s = 0.f;
#pragma unroll
    for (int e = 0; e < NE; ++e) {
        l[e] = expf(l[e] - m1);
        s += l[e];
    }
    const float inv = 1.f / s;

    // per-wave butterfly reduction of Pi (scores summed over the wave's 64 tokens)
    const int lane = tid & 63;
    float     myP  = 0.f;
#pragma unroll
    for (int e = 0; e < NE; ++e) {
        float r = l[e] * inv;
#pragma unroll
        for (int off = 32; off >= 1; off >>= 1) r += __shfl_xor(r, off, 64);
        if (lane == e) myP = r;
    }
    atomicAdd(&Ps[lane], myP);

    // expert selection counts
    atomicAdd(&Csh[i1], 1.f);
    atomicAdd(&Csh[i2], 1.f);

    // outputs: idx (as float) and normalized top-2 weights
    const float e2v = expf(m2 - m1);
    const float w1  = 1.f * inv;
    const float w2  = e2v * inv;
    const float iw  = 1.f / (w1 + w2);
    *(float2*)(out + (size_t)t * 2)                  = make_float2((float)i1, (float)i2);
    *(float2*)(out + (size_t)2 * TT + (size_t)t * 2) = make_float2(w1 * iw, w2 * iw);

    __syncthreads();
    if (tid < NE) {
        atomicAdd(&Pacc[tid], Ps[tid]);
        atomicAdd(&Cacc[tid], Csh[tid]);
    }
}

// ---------------- aux loss ----------------
__global__ void auxk(const float* __restrict__ Pacc, const float* __restrict__ Cacc,
                     float* __restrict__ out) {
    const int e  = threadIdx.x;
    const float Pi = Pacc[e] / (float)TT;
    const float fi = Cacc[e] * (float)NE / (float)(TT * TOPK);
    float v = Pi * fi;
#pragma unroll
    for (int off = 32; off >= 1; off >>= 1) v += __shfl_xor(v, off, 64);
    if (e == 0) out[(size_t)2 * TT * 2] = ALPHA * v;
}

extern "C" void kernel_launch(void* const* d_in, const int* in_sizes, int n_in,
                              void* d_out, int out_size, void* d_ws, size_t ws_size,
                              hipStream_t stream) {
    const float* x = (const float*)d_in[0];
    const float* w = (const float*)d_in[1];
    float* out  = (float*)d_out;
    float* part = (float*)d_ws;                        // CSPLIT*TT*NE floats = 16 MiB
    float* Pacc = part + (size_t)CSPLIT * TT * NE;     // 64 floats
    float* Cacc = Pacc + NE;                           // 64 floats

    hipMemsetAsync(Pacc, 0, 2 * NE * sizeof(float), stream);

    dim3 g1(TT / BT, CSPLIT);
    gate_gemm<<<g1, 256, 0, stream>>>(x, w, part);
    finalize<<<TT / 256, 256, 0, stream>>>(part, out, Pacc, Cacc);
    auxk<<<1, 64, 0, stream>>>(Pacc, Cacc, out);
}